// Round 1
// baseline (146.714 us; speedup 1.0000x reference)
//
#include <hip/hip_runtime.h>
#include <hip/hip_bf16.h>

#define NB 32
#define NP 4096
#define NM 12
#define NW 9
#define NC 64          // IN_C == OUT_C == 64
#define PN_PAD 4097
#define KDIM (NW * NC)     // 576
#define KSTEPS (KDIM / 32) // 18
#define AROW 584           // 576 + 8 pad (keeps 16B alignment, breaks bank aliasing)

typedef __attribute__((ext_vector_type(8))) short short8;
typedef __attribute__((ext_vector_type(4))) float float4v;

__device__ __forceinline__ unsigned short f32_to_bf16(float f) {
    union { float f; unsigned u; } v; v.f = f;
    unsigned r = v.u + 0x7FFFu + ((v.u >> 16) & 1u);  // round-nearest-even
    return (unsigned short)(r >> 16);
}

// Pre-swizzle weights (9, 64*64) fp32 -> bf16 in MFMA B-fragment order.
// Fragment element layout: idx = ((ks*4 + nt)*64 + lane)*8 + j
//   k = ks*32 + (lane>>4)*8 + j   (k = w*64 + i)
//   n = nt*16 + (lane & 15)       (n = o)
//   value = weights[w, n*64 + i]
__global__ void prep_weights(const float* __restrict__ w,
                             unsigned short* __restrict__ wsw) {
    int idx = blockIdx.x * 256 + threadIdx.x;
    if (idx >= KDIM * NC) return;
    int j    = idx & 7;
    int lane = (idx >> 3) & 63;
    int nt   = (idx >> 9) & 3;
    int ks   = idx >> 11;
    int k = ks * 32 + ((lane >> 4) * 8) + j;
    int n = nt * 16 + (lane & 15);
    int wi = k >> 6;
    int ii = k & 63;
    wsw[idx] = f32_to_bf16(w[wi * (NC * NC) + n * NC + ii]);
}

// One block per p. Phase 1: t[b, w*64+i] (32 x 576) in fp32 -> bf16 LDS tile.
// Phase 2: C[32 x 64] = A(32x576) * B(576x64) via mfma_f32_16x16x32_bf16.
__global__ __launch_bounds__(256)
void conv_main(const float* __restrict__ x,            // (32, 4097, 64)
               const unsigned short* __restrict__ wsw, // swizzled bf16 weights
               const float* __restrict__ bias,         // (64,)
               const float* __restrict__ ww,           // (4096, 12, 9)
               const int* __restrict__ nid,            // (4096, 12)
               const float* __restrict__ mask,         // (4096, 12)
               float* __restrict__ out)                // (32, 4096, 64)
{
    __shared__ __align__(16) unsigned short A[NB * AROW];
    __shared__ float s_w2[NM * NW];
    __shared__ int s_nid[NM];

    const int p = blockIdx.x;
    const int tid = threadIdx.x;

    if (tid < NM * NW) s_w2[tid] = ww[p * (NM * NW) + tid] * mask[p * NM + tid / NW];
    if (tid < NM) s_nid[tid] = nid[p * NM + tid];
    __syncthreads();

    // ---- Phase 1: gather + weighted sum -> A tile (bf16) ----
    {
        const int i  = tid & 63;
        const int b0 = tid >> 6;  // 0..3 ; thread covers b = b0 + 4*it
        float acc[8][9];
        #pragma unroll
        for (int it = 0; it < 8; ++it)
            #pragma unroll
            for (int w = 0; w < 9; ++w) acc[it][w] = 0.f;

        #pragma unroll 1
        for (int m = 0; m < NM; ++m) {
            const int nm = s_nid[m];
            float wv[9];
            #pragma unroll
            for (int w = 0; w < 9; ++w) wv[w] = s_w2[m * NW + w];
            float xv[8];
            #pragma unroll
            for (int it = 0; it < 8; ++it) {
                const int b = b0 + it * 4;
                xv[it] = x[(b * PN_PAD + nm) * NC + i];
            }
            #pragma unroll
            for (int it = 0; it < 8; ++it)
                #pragma unroll
                for (int w = 0; w < 9; ++w)
                    acc[it][w] = fmaf(wv[w], xv[it], acc[it][w]);
        }

        #pragma unroll
        for (int it = 0; it < 8; ++it) {
            const int b = b0 + it * 4;
            #pragma unroll
            for (int w = 0; w < 9; ++w)
                A[b * AROW + w * 64 + i] = f32_to_bf16(acc[it][w]);
        }
    }
    __syncthreads();

    // ---- Phase 2: MFMA GEMM, wave nt handles columns [nt*16, nt*16+16) ----
    {
        const int lane = tid & 63;
        const int nt   = tid >> 6;  // wave id = n-tile
        const int quad = lane >> 4;
        const int l15  = lane & 15;

        float4v acc0 = {0.f, 0.f, 0.f, 0.f};
        float4v acc1 = {0.f, 0.f, 0.f, 0.f};
        const short8* Bfrags = (const short8*)wsw;

        #pragma unroll
        for (int ks = 0; ks < KSTEPS; ++ks) {
            short8 bfrag = Bfrags[(ks * 4 + nt) * 64 + lane];
            const short8 a0 = *(const short8*)&A[(l15     ) * AROW + ks * 32 + quad * 8];
            const short8 a1 = *(const short8*)&A[(16 + l15) * AROW + ks * 32 + quad * 8];
            acc0 = __builtin_amdgcn_mfma_f32_16x16x32_bf16(a0, bfrag, acc0, 0, 0, 0);
            acc1 = __builtin_amdgcn_mfma_f32_16x16x32_bf16(a1, bfrag, acc1, 0, 0, 0);
        }

        const int o = nt * 16 + l15;
        const float bv = bias[o];
        #pragma unroll
        for (int reg = 0; reg < 4; ++reg) {
            const int r0 = quad * 4 + reg;        // b for acc0
            out[(r0 * NP + p) * NC + o] = acc0[reg] + bv;
            const int r1 = 16 + r0;               // b for acc1
            out[(r1 * NP + p) * NC + o] = acc1[reg] + bv;
        }
    }
}

extern "C" void kernel_launch(void* const* d_in, const int* in_sizes, int n_in,
                              void* d_out, int out_size, void* d_ws, size_t ws_size,
                              hipStream_t stream) {
    const float* x    = (const float*)d_in[0];
    const float* w    = (const float*)d_in[1];
    const float* bias = (const float*)d_in[2];
    const float* ww   = (const float*)d_in[3];
    const int*   nid  = (const int*)d_in[4];
    const float* mask = (const float*)d_in[5];
    float* out = (float*)d_out;
    unsigned short* wsw = (unsigned short*)d_ws;  // 73,728 B used

    hipLaunchKernelGGL(prep_weights, dim3((KDIM * NC + 255) / 256), dim3(256), 0, stream,
                       w, wsw);
    hipLaunchKernelGGL(conv_main, dim3(NP), dim3(256), 0, stream,
                       x, wsw, bias, ww, nid, mask, out);
}

// Round 2
// 144.919 us; speedup vs baseline: 1.0124x; 1.0124x over previous
//
#include <hip/hip_runtime.h>
#include <hip/hip_bf16.h>

#define NB 32
#define NP 4096
#define NM 12
#define NW 9
#define NC 64          // IN_C == OUT_C == 64
#define PN_PAD 4097
#define KDIM (NW * NC)     // 576
#define KSTEPS (KDIM / 32) // 18
#define AROW 584           // 576 + 8 pad shorts (16B-aligned rows)

#define WSW_BYTES (KDIM * NC * 2)      // 73728 B, bf16 swizzled weights
#define W2_OFFSET WSW_BYTES            // float w2d[(p*12+m)*12 + w]

typedef __attribute__((ext_vector_type(8))) short short8;
typedef __attribute__((ext_vector_type(4))) float float4v;

__device__ __forceinline__ unsigned short f32_to_bf16(float f) {
    union { float f; unsigned u; } v; v.f = f;
    unsigned r = v.u + 0x7FFFu + ((v.u >> 16) & 1u);  // RNE
    return (unsigned short)(r >> 16);
}

// Pack float4 -> 4 bf16 (round-to-nearest via +0x8000, then take high 16 bits)
__device__ __forceinline__ uint2 pack_bf16x4(float4v v) {
    union { float f; unsigned u; } a0, a1, a2, a3;
    a0.f = v[0]; a1.f = v[1]; a2.f = v[2]; a3.f = v[3];
    unsigned u0 = a0.u + 0x8000u, u1 = a1.u + 0x8000u;
    unsigned u2 = a2.u + 0x8000u, u3 = a3.u + 0x8000u;
    uint2 r;
    r.x = __builtin_amdgcn_perm(u1, u0, 0x07060302u);  // hi16(u1)<<16 | hi16(u0)
    r.y = __builtin_amdgcn_perm(u3, u2, 0x07060302u);
    return r;
}

// Prep: (a) swizzle weights fp32 -> bf16 in MFMA B-fragment order;
//       (b) w2d[(p*12+m)*12 + w] = ww[p,m,w] * mask[p,m]  (padded stride 12)
__global__ void prep(const float* __restrict__ w,
                     const float* __restrict__ ww,
                     const float* __restrict__ mask,
                     unsigned short* __restrict__ wsw,
                     float* __restrict__ w2d) {
    int idx = blockIdx.x * 256 + threadIdx.x;
    if (idx < KDIM * NC) {
        int j    = idx & 7;
        int lane = (idx >> 3) & 63;
        int nt   = (idx >> 9) & 3;
        int ks   = idx >> 11;
        int k = ks * 32 + ((lane >> 4) * 8) + j;   // k = w*64 + i
        int n = nt * 16 + (lane & 15);             // n = o
        int wi = k >> 6;
        int ii = k & 63;
        wsw[idx] = f32_to_bf16(w[wi * (NC * NC) + n * NC + ii]);
    }
    if (idx < NP * NM * NW) {
        int wq = idx % NW;
        int pm = idx / NW;       // p*12 + m
        w2d[pm * 12 + wq] = ww[idx] * mask[pm];
    }
}

// One block per p. Phase 1: t[b, w*64+i] (32 x 576) fp32 -> bf16 LDS tile,
// with w2/nid read via wave-uniform (scalar) loads. Phase 2: MFMA GEMM.
__global__ __launch_bounds__(256)
void conv_main(const float* __restrict__ x,            // (32, 4097, 64)
               const unsigned short* __restrict__ wsw, // swizzled bf16 weights
               const float* __restrict__ bias,         // (64,)
               const float* __restrict__ w2d,          // (4096, 12, 12-padded)
               const int* __restrict__ nid,            // (4096, 12)
               float* __restrict__ out)                // (32, 4096, 64)
{
    __shared__ __align__(16) unsigned short A[NB * AROW];

    const int p = blockIdx.x;
    const int tid = threadIdx.x;

    // ---- Phase 1 ----
    {
        const int i4 = tid & 15;   // float4 column within a 64-float row
        const int bs = tid >> 4;   // 0..15 ; handles b = bs and bs+16
        const float4v* x4 = (const float4v*)x;
        const float* w2p = w2d + p * (NM * 12);
        const int* nidp = nid + p * NM;

        int nm[NM];
        #pragma unroll
        for (int m = 0; m < NM; ++m) nm[m] = nidp[m];  // uniform -> SGPRs

        float4v acc0[NW], acc1[NW];
        #pragma unroll
        for (int w = 0; w < NW; ++w) {
            acc0[w] = (float4v){0.f, 0.f, 0.f, 0.f};
            acc1[w] = (float4v){0.f, 0.f, 0.f, 0.f};
        }

        #pragma unroll 2
        for (int m = 0; m < NM; ++m) {
            const float4v xv0 = x4[(bs * PN_PAD + nm[m]) * 16 + i4];
            const float4v xv1 = x4[((bs + 16) * PN_PAD + nm[m]) * 16 + i4];
            #pragma unroll
            for (int w = 0; w < NW; ++w) {
                const float wv = w2p[m * 12 + w];  // uniform -> s_load
                acc0[w] += wv * xv0;
                acc1[w] += wv * xv1;
            }
        }

        #pragma unroll
        for (int w = 0; w < NW; ++w) {
            *(uint2*)&A[bs * AROW + w * 64 + i4 * 4] = pack_bf16x4(acc0[w]);
            *(uint2*)&A[(bs + 16) * AROW + w * 64 + i4 * 4] = pack_bf16x4(acc1[w]);
        }
    }
    __syncthreads();

    // ---- Phase 2: C[32x64] = A(32x576) * B(576x64), mfma 16x16x32 bf16 ----
    {
        const int lane = tid & 63;
        const int nt   = tid >> 6;  // wave id = n-tile (16 output cols)
        const int quad = lane >> 4;
        const int l15  = lane & 15;

        float4v acc0 = {0.f, 0.f, 0.f, 0.f};
        float4v acc1 = {0.f, 0.f, 0.f, 0.f};
        const short8* Bfrags = (const short8*)wsw;

        #pragma unroll
        for (int ks = 0; ks < KSTEPS; ++ks) {
            short8 bfrag = Bfrags[(ks * 4 + nt) * 64 + lane];
            const short8 a0 = *(const short8*)&A[(l15     ) * AROW + ks * 32 + quad * 8];
            const short8 a1 = *(const short8*)&A[(16 + l15) * AROW + ks * 32 + quad * 8];
            acc0 = __builtin_amdgcn_mfma_f32_16x16x32_bf16(a0, bfrag, acc0, 0, 0, 0);
            acc1 = __builtin_amdgcn_mfma_f32_16x16x32_bf16(a1, bfrag, acc1, 0, 0, 0);
        }

        const int o = nt * 16 + l15;
        const float bv = bias[o];
        #pragma unroll
        for (int reg = 0; reg < 4; ++reg) {
            const int r0 = quad * 4 + reg;
            out[(r0 * NP + p) * NC + o] = acc0[reg] + bv;
            const int r1 = 16 + r0;
            out[(r1 * NP + p) * NC + o] = acc1[reg] + bv;
        }
    }
}

extern "C" void kernel_launch(void* const* d_in, const int* in_sizes, int n_in,
                              void* d_out, int out_size, void* d_ws, size_t ws_size,
                              hipStream_t stream) {
    const float* x    = (const float*)d_in[0];
    const float* w    = (const float*)d_in[1];
    const float* bias = (const float*)d_in[2];
    const float* ww   = (const float*)d_in[3];
    const int*   nid  = (const int*)d_in[4];
    const float* mask = (const float*)d_in[5];
    float* out = (float*)d_out;
    unsigned short* wsw = (unsigned short*)d_ws;
    float* w2d = (float*)((char*)d_ws + W2_OFFSET);

    const int prep_elems = NP * NM * NW;  // 442368 > 36864
    hipLaunchKernelGGL(prep, dim3((prep_elems + 255) / 256), dim3(256), 0, stream,
                       w, ww, mask, wsw, w2d);
    hipLaunchKernelGGL(conv_main, dim3(NP), dim3(256), 0, stream,
                       x, wsw, bias, w2d, nid, out);
}

// Round 3
// 142.560 us; speedup vs baseline: 1.0291x; 1.0165x over previous
//
#include <hip/hip_runtime.h>
#include <hip/hip_bf16.h>

#define NB 32
#define NP 4096
#define NM 12
#define NW 9
#define NC 64          // IN_C == OUT_C == 64
#define PN_PAD 4097
#define KDIM (NW * NC)     // 576
#define KSTEPS (KDIM / 32) // 18
#define AROW 584           // 576 + 8 pad shorts (16B-aligned rows)

#define WSW_BYTES (KDIM * NC * 2)      // 73728 B, bf16 swizzled weights
#define W2_OFFSET WSW_BYTES            // float w2d[(p*12+m)*12 + w]

typedef __attribute__((ext_vector_type(8))) short short8;
typedef __attribute__((ext_vector_type(4))) float float4v;

__device__ __forceinline__ unsigned short f32_to_bf16(float f) {
    union { float f; unsigned u; } v; v.f = f;
    unsigned r = v.u + 0x7FFFu + ((v.u >> 16) & 1u);  // RNE
    return (unsigned short)(r >> 16);
}

// Pack float4 -> 4 bf16 (round via +0x8000, take high 16 bits)
__device__ __forceinline__ uint2 pack_bf16x4(float4v v) {
    union { float f; unsigned u; } a0, a1, a2, a3;
    a0.f = v[0]; a1.f = v[1]; a2.f = v[2]; a3.f = v[3];
    unsigned u0 = a0.u + 0x8000u, u1 = a1.u + 0x8000u;
    unsigned u2 = a2.u + 0x8000u, u3 = a3.u + 0x8000u;
    uint2 r;
    r.x = __builtin_amdgcn_perm(u1, u0, 0x07060302u);  // hi16(u1)<<16 | hi16(u0)
    r.y = __builtin_amdgcn_perm(u3, u2, 0x07060302u);
    return r;
}

// Prep: (a) swizzle weights fp32 -> bf16 in MFMA B-fragment order;
//       (b) w2d[(p*12+m)*12 + w] = ww[p,m,w] * mask[p,m]  (padded stride 12)
__global__ void prep(const float* __restrict__ w,
                     const float* __restrict__ ww,
                     const float* __restrict__ mask,
                     unsigned short* __restrict__ wsw,
                     float* __restrict__ w2d) {
    int idx = blockIdx.x * 256 + threadIdx.x;
    if (idx < KDIM * NC) {
        int j    = idx & 7;
        int lane = (idx >> 3) & 63;
        int nt   = (idx >> 9) & 3;
        int ks   = idx >> 11;
        int k = ks * 32 + ((lane >> 4) * 8) + j;   // k = w*64 + i
        int n = nt * 16 + (lane & 15);             // n = o
        int wi = k >> 6;
        int ii = k & 63;
        wsw[idx] = f32_to_bf16(w[wi * (NC * NC) + n * NC + ii]);
    }
    if (idx < NP * NM * NW) {
        int wq = idx % NW;
        int pm = idx / NW;       // p*12 + m
        w2d[pm * 12 + wq] = ww[idx] * mask[pm];
    }
}

// One block (512 threads) per p.
// Phase 1: t[b, w*64+i] (32 x 576) fp32 -> bf16 LDS tile. Thread = (b, ch-quad):
//          36 accumulators, 12 gather loads issued ONCE (two prefetch groups of 6).
// Phase 2: 8 waves, each one 16x16 MFMA tile (mt = wid>>2, nt = wid&3).
__global__ __launch_bounds__(512)
void conv_main(const float* __restrict__ x,            // (32, 4097, 64)
               const unsigned short* __restrict__ wsw, // swizzled bf16 weights
               const float* __restrict__ bias,         // (64,)
               const float* __restrict__ w2d,          // (4096, 12, 12-padded)
               const int* __restrict__ nid,            // (4096, 12)
               float* __restrict__ out)                // (32, 4096, 64)
{
    __shared__ __align__(16) unsigned short A[NB * AROW];

    const int p = blockIdx.x;
    const int tid = threadIdx.x;

    // ---- Phase 1 ----
    {
        const int i4 = tid & 15;   // float4 column within a 64-float row
        const int b  = tid >> 4;   // 0..31
        const float4v* x4 = (const float4v*)x;
        const float* w2p = w2d + p * (NM * 12);
        const int* nidp = nid + p * NM;

        int nm[NM];
        #pragma unroll
        for (int m = 0; m < NM; ++m) nm[m] = nidp[m];  // uniform -> SGPRs

        float4v acc[NW];
        #pragma unroll
        for (int w = 0; w < NW; ++w) acc[w] = (float4v){0.f, 0.f, 0.f, 0.f};

        // group 1: prefetch m = 0..5
        float4v xv0[6];
        #pragma unroll
        for (int m = 0; m < 6; ++m)
            xv0[m] = x4[(b * PN_PAD + nm[m]) * 16 + i4];
        // group 2: prefetch m = 6..11 (issues while group-1 FMAs run)
        float4v xv1[6];
        #pragma unroll
        for (int m = 0; m < 6; ++m)
            xv1[m] = x4[(b * PN_PAD + nm[6 + m]) * 16 + i4];

        #pragma unroll
        for (int m = 0; m < 6; ++m) {
            #pragma unroll
            for (int w = 0; w < NW; ++w)
                acc[w] += w2p[m * 12 + w] * xv0[m];
        }
        #pragma unroll
        for (int m = 0; m < 6; ++m) {
            #pragma unroll
            for (int w = 0; w < NW; ++w)
                acc[w] += w2p[(6 + m) * 12 + w] * xv1[m];
        }

        #pragma unroll
        for (int w = 0; w < NW; ++w)
            *(uint2*)&A[b * AROW + w * 64 + i4 * 4] = pack_bf16x4(acc[w]);
    }
    __syncthreads();

    // ---- Phase 2: C[32x64] = A(32x576) * B(576x64), mfma 16x16x32 bf16 ----
    {
        const int lane = tid & 63;
        const int wid  = tid >> 6;   // 0..7
        const int nt   = wid & 3;    // n-tile (16 output cols)
        const int mt   = wid >> 2;   // m-tile (16 b-rows)
        const int quad = lane >> 4;
        const int l15  = lane & 15;

        float4v acc = {0.f, 0.f, 0.f, 0.f};
        const short8* Bfrags = (const short8*)wsw;
        const int arow = mt * 16 + l15;

        #pragma unroll
        for (int ks = 0; ks < KSTEPS; ++ks) {
            short8 bfrag = Bfrags[(ks * 4 + nt) * 64 + lane];
            const short8 a = *(const short8*)&A[arow * AROW + ks * 32 + quad * 8];
            acc = __builtin_amdgcn_mfma_f32_16x16x32_bf16(a, bfrag, acc, 0, 0, 0);
        }

        const int o = nt * 16 + l15;
        const float bv = bias[o];
        #pragma unroll
        for (int reg = 0; reg < 4; ++reg) {
            const int b = mt * 16 + quad * 4 + reg;
            out[(b * NP + p) * NC + o] = acc[reg] + bv;
        }
    }
}

extern "C" void kernel_launch(void* const* d_in, const int* in_sizes, int n_in,
                              void* d_out, int out_size, void* d_ws, size_t ws_size,
                              hipStream_t stream) {
    const float* x    = (const float*)d_in[0];
    const float* w    = (const float*)d_in[1];
    const float* bias = (const float*)d_in[2];
    const float* ww   = (const float*)d_in[3];
    const int*   nid  = (const int*)d_in[4];
    const float* mask = (const float*)d_in[5];
    float* out = (float*)d_out;
    unsigned short* wsw = (unsigned short*)d_ws;
    float* w2d = (float*)((char*)d_ws + W2_OFFSET);

    const int prep_elems = NP * NM * NW;  // 442368 covers both prep jobs
    hipLaunchKernelGGL(prep, dim3((prep_elems + 255) / 256), dim3(256), 0, stream,
                       w, ww, mask, wsw, w2d);
    hipLaunchKernelGGL(conv_main, dim3(NP), dim3(512), 0, stream,
                       x, wsw, bias, w2d, nid, out);
}

// Round 4
// 141.305 us; speedup vs baseline: 1.0383x; 1.0089x over previous
//
#include <hip/hip_runtime.h>
#include <hip/hip_bf16.h>

#define NB 32
#define NP 4096
#define NM 12
#define NW 9
#define NC 64          // IN_C == OUT_C == 64
#define PN_PAD 4097
#define KDIM (NW * NC)     // 576
#define KSTEPS (KDIM / 32) // 18
#define AROW 584           // 576 + 8 pad shorts (16B-aligned rows)

#define WSW_BYTES (KDIM * NC * 2)      // 73728 B, bf16 swizzled weights
#define W2_OFFSET WSW_BYTES            // float w2d[(p*12+m)*12 + w]

typedef __attribute__((ext_vector_type(8))) short short8;
typedef __attribute__((ext_vector_type(4))) float float4v;

__device__ __forceinline__ unsigned short f32_to_bf16(float f) {
    union { float f; unsigned u; } v; v.f = f;
    unsigned r = v.u + 0x7FFFu + ((v.u >> 16) & 1u);  // RNE
    return (unsigned short)(r >> 16);
}

// Pack float4 -> 4 bf16 (round via +0x8000, take high 16 bits)
__device__ __forceinline__ uint2 pack_bf16x4(float4v v) {
    union { float f; unsigned u; } a0, a1, a2, a3;
    a0.f = v[0]; a1.f = v[1]; a2.f = v[2]; a3.f = v[3];
    unsigned u0 = a0.u + 0x8000u, u1 = a1.u + 0x8000u;
    unsigned u2 = a2.u + 0x8000u, u3 = a3.u + 0x8000u;
    uint2 r;
    r.x = __builtin_amdgcn_perm(u1, u0, 0x07060302u);  // hi16(u1)<<16 | hi16(u0)
    r.y = __builtin_amdgcn_perm(u3, u2, 0x07060302u);
    return r;
}

// Prep: (a) swizzle weights fp32 -> bf16 in MFMA B-fragment order;
//       (b) w2d[(p*12+m)*12 + w] = ww[p,m,w] * mask[p,m]  (padded stride 12)
__global__ void prep(const float* __restrict__ w,
                     const float* __restrict__ ww,
                     const float* __restrict__ mask,
                     unsigned short* __restrict__ wsw,
                     float* __restrict__ w2d) {
    int idx = blockIdx.x * 256 + threadIdx.x;
    if (idx < KDIM * NC) {
        int j    = idx & 7;
        int lane = (idx >> 3) & 63;
        int nt   = (idx >> 9) & 3;
        int ks   = idx >> 11;
        int k = ks * 32 + ((lane >> 4) * 8) + j;   // k = w*64 + i
        int n = nt * 16 + (lane & 15);             // n = o
        int wi = k >> 6;
        int ii = k & 63;
        wsw[idx] = f32_to_bf16(w[wi * (NC * NC) + n * NC + ii]);
    }
    if (idx < NP * NM * NW) {
        int wq = idx % NW;
        int pm = idx / NW;       // p*12 + m
        w2d[pm * 12 + wq] = ww[idx] * mask[pm];
    }
}

// One block (512 threads) per p.
// __launch_bounds__(512, 4): 4 waves/EU target -> 128-VGPR budget so the
// 12 gather loads (48 VGPRs) + 36 accumulators stay live simultaneously.
// Phase 1: t[b, w*64+i] (32 x 576) fp32 -> bf16 LDS tile; thread = (b, ch-quad).
// Phase 2: 8 waves, each one 16x16 MFMA tile (mt = wid>>2, nt = wid&3).
__global__ __launch_bounds__(512, 4)
void conv_main(const float* __restrict__ x,            // (32, 4097, 64)
               const unsigned short* __restrict__ wsw, // swizzled bf16 weights
               const float* __restrict__ bias,         // (64,)
               const float* __restrict__ w2d,          // (4096, 12, 12-padded)
               const int* __restrict__ nid,            // (4096, 12)
               float* __restrict__ out)                // (32, 4096, 64)
{
    __shared__ __align__(16) unsigned short A[NB * AROW];

    const int p = blockIdx.x;
    const int tid = threadIdx.x;

    // ---- Phase 1 ----
    {
        const int i4 = tid & 15;   // float4 column within a 64-float row
        const int b  = tid >> 4;   // 0..31
        const float4v* x4 = (const float4v*)x;
        const float* w2p = w2d + p * (NM * 12);
        const int* nidp = nid + p * NM;

        int nm[NM];
        #pragma unroll
        for (int m = 0; m < NM; ++m) nm[m] = nidp[m];  // uniform -> SGPRs

        // Issue ALL 12 gather loads before any use: one latency exposure.
        float4v xv[NM];
        #pragma unroll
        for (int m = 0; m < NM; ++m)
            xv[m] = x4[(b * PN_PAD + nm[m]) * 16 + i4];

        float4v acc[NW];
        #pragma unroll
        for (int w = 0; w < NW; ++w) acc[w] = (float4v){0.f, 0.f, 0.f, 0.f};

        #pragma unroll
        for (int m = 0; m < NM; ++m) {
            #pragma unroll
            for (int w = 0; w < NW; ++w)
                acc[w] += w2p[m * 12 + w] * xv[m];
        }

        #pragma unroll
        for (int w = 0; w < NW; ++w)
            *(uint2*)&A[b * AROW + w * 64 + i4 * 4] = pack_bf16x4(acc[w]);
    }
    __syncthreads();

    // ---- Phase 2: C[32x64] = A(32x576) * B(576x64), mfma 16x16x32 bf16 ----
    {
        const int lane = tid & 63;
        const int wid  = tid >> 6;   // 0..7
        const int nt   = wid & 3;    // n-tile (16 output cols)
        const int mt   = wid >> 2;   // m-tile (16 b-rows)
        const int quad = lane >> 4;
        const int l15  = lane & 15;

        float4v acc = {0.f, 0.f, 0.f, 0.f};
        const short8* Bfrags = (const short8*)wsw;
        const int arow = mt * 16 + l15;

        #pragma unroll
        for (int ks = 0; ks < KSTEPS; ++ks) {
            short8 bfrag = Bfrags[(ks * 4 + nt) * 64 + lane];
            const short8 a = *(const short8*)&A[arow * AROW + ks * 32 + quad * 8];
            acc = __builtin_amdgcn_mfma_f32_16x16x32_bf16(a, bfrag, acc, 0, 0, 0);
        }

        const int o = nt * 16 + l15;
        const float bv = bias[o];
        #pragma unroll
        for (int reg = 0; reg < 4; ++reg) {
            const int b = mt * 16 + quad * 4 + reg;
            out[(b * NP + p) * NC + o] = acc[reg] + bv;
        }
    }
}

extern "C" void kernel_launch(void* const* d_in, const int* in_sizes, int n_in,
                              void* d_out, int out_size, void* d_ws, size_t ws_size,
                              hipStream_t stream) {
    const float* x    = (const float*)d_in[0];
    const float* w    = (const float*)d_in[1];
    const float* bias = (const float*)d_in[2];
    const float* ww   = (const float*)d_in[3];
    const int*   nid  = (const int*)d_in[4];
    const float* mask = (const float*)d_in[5];
    float* out = (float*)d_out;
    unsigned short* wsw = (unsigned short*)d_ws;
    float* w2d = (float*)((char*)d_ws + W2_OFFSET);

    const int prep_elems = NP * NM * NW;  // 442368 covers both prep jobs
    hipLaunchKernelGGL(prep, dim3((prep_elems + 255) / 256), dim3(256), 0, stream,
                       w, ww, mask, wsw, w2d);
    hipLaunchKernelGGL(conv_main, dim3(NP), dim3(512), 0, stream,
                       x, wsw, bias, w2d, nid, out);
}